// Round 7
// baseline (252.108 us; speedup 1.0000x reference)
//
#include <hip/hip_runtime.h>
#include <hip/hip_bf16.h>
#include <stdint.h>

// CrossAttention: B=8, C=256, H=W=64 (N=4096), CR=64.
// proj chain (MFMA): wprep -> transpose(gui) -> projK, projV -> transpose(src) -> projQ
//   Qb/Kb frag-linear: [tile(64px)][frag f<8][lane*8] bf16.
//   VF frag-linear:    [b][kt][half][cf<8][kk<2][lane][8] bf16 (PV A-operand frags).
// attn: BARRIER-FREE. grid 1024 (XCD-swizzled: batch==XCD), 4 waves/block,
//   wave-local 16q x 128ch; K & V stream global->reg (frag-linear, coalesced);
//   P per-wave in LDS (8 KB total); no __syncthreads anywhere.

#define B_ 8
#define C_ 256
#define N_ 4096
#define CR_ 64

typedef unsigned short u16;
typedef __attribute__((ext_vector_type(8))) __bf16 bf16x8;
typedef __attribute__((ext_vector_type(4))) float f32x4;

__device__ __forceinline__ u16 f2bf(float f) {
  union { float f; unsigned int u; } v; v.f = f;
  unsigned int r = (v.u + 0x7fffu + ((v.u >> 16) & 1u)) >> 16;
  return (u16)r;
}
__device__ __forceinline__ unsigned int cvtpk(float a, float b) {
  unsigned int r;
  asm("v_cvt_pk_bf16_f32 %0, %1, %2" : "=v"(r) : "v"(a), "v"(b));
  return r;
}

// ---------------- Weight prep ----------------
__global__ __launch_bounds__(256) void wprep_kernel(
    const float* __restrict__ Wq, const float* __restrict__ Wk,
    const float* __restrict__ Wv, u16* __restrict__ Wb)
{
  const int i = (blockIdx.x * 256 + threadIdx.x) * 4;
  const int row = i >> 8;
  float4 v;
  float s = 1.0f;
  if (row < 64)       { v = *(const float4*)(Wq + i); s = 1.44269504f; }
  else if (row < 128) { v = *(const float4*)(Wk + i - 64 * 256); }
  else                { v = *(const float4*)(Wv + i - 128 * 256); }
  u16* o = Wb + i;
  o[0] = f2bf(v.x * s); o[1] = f2bf(v.y * s);
  o[2] = f2bf(v.z * s); o[3] = f2bf(v.w * s);
}

// ---------------- Transpose [C][N] f32 -> [N][C] bf16 ----------------------
__global__ __launch_bounds__(256) void transpose_kernel(
    const float* __restrict__ in, u16* __restrict__ outT)
{
  __shared__ u16 Tl[64 * 66];
  const int t = threadIdx.x;
  const int px0 = blockIdx.x * 64, ch0 = blockIdx.y * 64, b = blockIdx.z;
  const float* ip = in + ((size_t)(b * C_ + ch0)) * N_ + px0;
  const int cx = t >> 4, p4 = (t & 15) * 4;
#pragma unroll
  for (int p = 0; p < 4; ++p) {
    const int ch = cx + p * 16;
    float4 v = *(const float4*)(ip + (size_t)ch * N_ + p4);
    Tl[(p4 + 0) * 66 + ch] = f2bf(v.x);
    Tl[(p4 + 1) * 66 + ch] = f2bf(v.y);
    Tl[(p4 + 2) * 66 + ch] = f2bf(v.z);
    Tl[(p4 + 3) * 66 + ch] = f2bf(v.w);
  }
  __syncthreads();
  const int row = t >> 3, seg = t & 7;
  u16* op = outT + ((size_t)(b * N_) + px0) * C_ + ch0 + seg * 8;
#pragma unroll
  for (int p = 0; p < 2; ++p) {
    const int r2 = row + p * 32;
    *(uint4*)(op + (size_t)r2 * C_) = *(const uint4*)(&Tl[r2 * 66 + seg * 8]);
  }
}

// ---------------- Q/K projection (MFMA), frag-linear output ----------------
__global__ __launch_bounds__(128) void projqk_kernel(
    const u16* __restrict__ inT, const u16* __restrict__ W64, u16* __restrict__ dst)
{
  __shared__ u16 Tl[2 * 64 * 72];
  const int t = threadIdx.x, lane = t & 63, wave = t >> 6;
  const int lg = lane >> 4, lm = lane & 15;
  const int b = blockIdx.y;
  const int px0 = blockIdx.x * 128 + wave * 64;
  const u16* ib = inT + ((size_t)(b * N_) + px0) * C_;

  f32x4 acc[4][4];
  const f32x4 z4 = {0.f, 0.f, 0.f, 0.f};
#pragma unroll
  for (int i = 0; i < 4; ++i)
#pragma unroll
    for (int j = 0; j < 4; ++j) acc[i][j] = z4;

  for (int ks = 0; ks < 8; ++ks) {
    bf16x8 wf[4], pf[4];
#pragma unroll
    for (int mi = 0; mi < 4; ++mi)
      wf[mi] = *(const bf16x8*)(W64 + (mi * 16 + lm) * C_ + ks * 32 + lg * 8);
#pragma unroll
    for (int ni = 0; ni < 4; ++ni)
      pf[ni] = *(const bf16x8*)(ib + (size_t)(ni * 16 + lm) * C_ + ks * 32 + lg * 8);
#pragma unroll
    for (int mi = 0; mi < 4; ++mi)
#pragma unroll
      for (int ni = 0; ni < 4; ++ni)
        acc[mi][ni] = __builtin_amdgcn_mfma_f32_16x16x32_bf16(wf[mi], pf[ni], acc[mi][ni], 0, 0, 0);
  }

  u16* tw = Tl + wave * 64 * 72;
#pragma unroll
  for (int mi = 0; mi < 4; ++mi)
#pragma unroll
    for (int ni = 0; ni < 4; ++ni)
#pragma unroll
      for (int rp = 0; rp < 2; ++rp)
        *(unsigned int*)&tw[(ni * 16 + lm) * 72 + mi * 16 + lg * 4 + rp * 2] =
            cvtpk(acc[mi][ni][rp * 2], acc[mi][ni][rp * 2 + 1]);

  const int tt = b * 64 + blockIdx.x * 2 + wave;
  u16* op = dst + (size_t)tt * 4096 + lane * 8;
#pragma unroll
  for (int f = 0; f < 8; ++f)
    *(uint4*)(op + f * 512) =
        *(const uint4*)(&Tl[(wave * 64 + (f >> 1) * 16 + lm) * 72 + (f & 1) * 32 + lg * 8]);
}

// ---------------- V projection (MFMA) -> VF frag-linear --------------------
// grid (32 px-blocks, B, 2 half), 128 thr = 2 waves; wave = 64 ch (cf = wave*4..+3).
// VF elem offset: b*1048576 + kt*16384 + half*8192 + cf*1024 + kk*512 + lane*8.
__global__ __launch_bounds__(128) void projv_kernel(
    const u16* __restrict__ inT, const u16* __restrict__ Wv256,
    const float* __restrict__ bv, u16* __restrict__ VF)
{
  __shared__ u16 Tl[2 * 64 * 72];
  const int t = threadIdx.x, lane = t & 63, wave = t >> 6;
  const int lg = lane >> 4, lm = lane & 15;
  const int b = blockIdx.y;
  const int half = blockIdx.z;
  const int px0 = blockIdx.x * 128;
  const int chb = half * 128 + wave * 64;
  const u16* ib = inT + ((size_t)(b * N_) + px0) * C_;
  const u16* wb = Wv256 + (size_t)chb * C_;
  u16* tw = Tl + wave * 64 * 72;

  f32x4 bq[4];
#pragma unroll
  for (int mi = 0; mi < 4; ++mi)
    bq[mi] = *(const f32x4*)(bv + chb + mi * 16 + lg * 4);

  const f32x4 z4 = {0.f, 0.f, 0.f, 0.f};
  for (int pg = 0; pg < 2; ++pg) {
    f32x4 acc[4][4];
#pragma unroll
    for (int i = 0; i < 4; ++i)
#pragma unroll
      for (int j = 0; j < 4; ++j) acc[i][j] = z4;
    for (int ks = 0; ks < 8; ++ks) {
      bf16x8 wf[4], pf[4];
#pragma unroll
      for (int mi = 0; mi < 4; ++mi)
        wf[mi] = *(const bf16x8*)(wb + (mi * 16 + lm) * C_ + ks * 32 + lg * 8);
#pragma unroll
      for (int ni = 0; ni < 4; ++ni)
        pf[ni] = *(const bf16x8*)(ib + (size_t)(pg * 64 + ni * 16 + lm) * C_ + ks * 32 + lg * 8);
#pragma unroll
      for (int mi = 0; mi < 4; ++mi)
#pragma unroll
        for (int ni = 0; ni < 4; ++ni)
          acc[mi][ni] = __builtin_amdgcn_mfma_f32_16x16x32_bf16(wf[mi], pf[ni], acc[mi][ni], 0, 0, 0);
    }
    // D[ch][px] -> Tl[ch_local][px_local] (wave-local; DS ops in-order per wave)
#pragma unroll
    for (int mi = 0; mi < 4; ++mi)
#pragma unroll
      for (int ni = 0; ni < 4; ++ni)
#pragma unroll
        for (int r = 0; r < 4; ++r)
          tw[(mi * 16 + lg * 4 + r) * 72 + ni * 16 + lm] = f2bf(acc[mi][ni][r] + bq[mi][r]);
    // read frags and store contiguous 1KB chunks
    const int kt = blockIdx.x * 2 + pg;
    u16* vo = VF + ((size_t)b << 20) + kt * 16384 + half * 8192;
#pragma unroll
    for (int cfl = 0; cfl < 4; ++cfl)
#pragma unroll
      for (int kk = 0; kk < 2; ++kk)
        *(uint4*)(vo + (wave * 4 + cfl) * 1024 + kk * 512 + lane * 8) =
            *(const uint4*)(&tw[(cfl * 16 + lm) * 72 + kk * 32 + lg * 8]);
  }
}

// ---------------- Flash attention (barrier-free) ----------------
__global__ __launch_bounds__(256, 3) void attn_kernel(
    const u16* __restrict__ Qb, const u16* __restrict__ Kb, const u16* __restrict__ VF,
    const float* __restrict__ source, const float* __restrict__ gamma,
    float* __restrict__ out)
{
  __shared__ char smem[8192];  // P only: 4 waves x 16q x 128B

  const int bid = blockIdx.x;
  const int swz = (bid & 7) * 128 + (bid >> 3);  // XCD x -> batch x
  const int qt = swz & 63;
  const int half = (swz >> 6) & 1;
  const int b = swz >> 7;

  const int t = threadIdx.x;
  const int lane = t & 63;
  const int wave = t >> 6;
  const int lg = lane >> 4;
  const int lm = lane & 15;
  const int q0 = qt * 64;
  const int sw = lm & 7;

  bf16x8 aq[2];
  {
    const u16* qp = Qb + (((size_t)(b * 64 + qt) * 8 + wave * 2) * 512) + lane * 8;
    aq[0] = *(const bf16x8*)qp;
    aq[1] = *(const bf16x8*)(qp + 512);
  }

  const u16* KbT = Kb + (size_t)b * N_ * CR_;
  const u16* VFb = VF + ((size_t)b << 20) + half * 8192;

  f32x4 accv[8];
  const f32x4 zero4 = {0.f, 0.f, 0.f, 0.f};
#pragma unroll
  for (int i = 0; i < 8; ++i) accv[i] = zero4;
  float mrow = -1e30f, lrow = 0.f;

  bf16x8 kC[8], vf[8];
  char* pslice = smem + wave * 2048 + lm * 128;

#define LOADK(KT) do {                                                       \
    const u16* kb_ = KbT + (size_t)(KT) * 4096 + lane * 8;                   \
    _Pragma("unroll")                                                        \
    for (int f = 0; f < 8; ++f)                                              \
      kC[f] = *(const bf16x8*)(kb_ + f * 512);                               \
  } while (0)

  LOADK(0);

  for (int kt = 0; kt < 64; ++kt) {
    const u16* vb = VFb + (size_t)kt * 16384 + lane * 8;
    // V kk=0 frags early (consumed ~softmax later)
#pragma unroll
    for (int cf = 0; cf < 8; ++cf)
      vf[cf] = *(const bf16x8*)(vb + cf * 1024);

    // S^T = mfma(A=K, B=Q): D[key=kf*16+lg*4+r][q=lm]
    f32x4 sf[4];
    __builtin_amdgcn_s_setprio(1);
#pragma unroll
    for (int kf = 0; kf < 4; ++kf) {
      sf[kf] = zero4;
      sf[kf] = __builtin_amdgcn_mfma_f32_16x16x32_bf16(kC[kf * 2], aq[0], sf[kf], 0, 0, 0);
      sf[kf] = __builtin_amdgcn_mfma_f32_16x16x32_bf16(kC[kf * 2 + 1], aq[1], sf[kf], 0, 0, 0);
    }
    __builtin_amdgcn_s_setprio(0);

    // prefetch K(t+1) (kC regs free after MFMA issue)
    const int ktn = (kt + 1 < 64) ? kt + 1 : 63;
    LOADK(ktn);

    // online softmax (all in-lane; key-major so only 2 shfls)
    float v_ = sf[0][0];
#pragma unroll
    for (int kf = 0; kf < 4; ++kf)
#pragma unroll
      for (int r = 0; r < 4; ++r) v_ = fmaxf(v_, sf[kf][r]);
    v_ = fmaxf(v_, __shfl_xor(v_, 16));
    v_ = fmaxf(v_, __shfl_xor(v_, 32));
    if (!__all(v_ <= mrow + 8.0f)) {
      float mn_ = fmaxf(mrow, v_);
      float sc_ = exp2f(mrow - mn_);
      mrow = mn_;
      lrow *= sc_;
#pragma unroll
      for (int cf = 0; cf < 8; ++cf)
#pragma unroll
        for (int r = 0; r < 4; ++r) accv[cf][r] *= sc_;
    }
    float s_ = 0.f;
#pragma unroll
    for (int kf = 0; kf < 4; ++kf)
#pragma unroll
      for (int r = 0; r < 4; ++r) {
        float e_ = exp2f(sf[kf][r] - mrow);
        sf[kf][r] = e_;
        s_ += e_;
      }
    s_ += __shfl_xor(s_, 16);
    s_ += __shfl_xor(s_, 32);
    lrow += s_;

    // P -> LDS (wave-local, chunk-XOR swizzle), read back as B-frags
#pragma unroll
    for (int kf = 0; kf < 4; ++kf) {
      uint2 w2_;
      w2_.x = cvtpk(sf[kf][0], sf[kf][1]);
      w2_.y = cvtpk(sf[kf][2], sf[kf][3]);
      *reinterpret_cast<uint2*>(
          pslice + (((kf * 2 + (lg >> 1)) ^ sw) << 4) + ((lg & 1) << 3)) = w2_;
    }
    bf16x8 pb0 = *reinterpret_cast<const bf16x8*>(pslice + ((lg ^ sw) << 4));
    bf16x8 pb1 = *reinterpret_cast<const bf16x8*>(pslice + (((4 + lg) ^ sw) << 4));

    // PV kk=0
    __builtin_amdgcn_s_setprio(1);
#pragma unroll
    for (int cf = 0; cf < 8; ++cf)
      accv[cf] = __builtin_amdgcn_mfma_f32_16x16x32_bf16(vf[cf], pb0, accv[cf], 0, 0, 0);
    __builtin_amdgcn_s_setprio(0);
    // V kk=1 frags (reuse regs), then PV kk=1
#pragma unroll
    for (int cf = 0; cf < 8; ++cf)
      vf[cf] = *(const bf16x8*)(vb + cf * 1024 + 512);
    __builtin_amdgcn_s_setprio(1);
#pragma unroll
    for (int cf = 0; cf < 8; ++cf)
      accv[cf] = __builtin_amdgcn_mfma_f32_16x16x32_bf16(vf[cf], pb1, accv[cf], 0, 0, 0);
    __builtin_amdgcn_s_setprio(0);
  }

  // ---- epilogue: out[b][ch][q0+wave*16+lm] = accv*inv + source ----
  const float inv = gamma[0] / lrow;
#pragma unroll
  for (int cf = 0; cf < 8; ++cf)
#pragma unroll
    for (int r = 0; r < 4; ++r) {
      const int ch = half * 128 + cf * 16 + lg * 4 + r;
      size_t gi = ((size_t)(b * C_ + ch)) * N_ + q0 + wave * 16 + lm;
      out[gi] = accv[cf][r] * inv + source[gi];
    }
}

extern "C" void kernel_launch(void* const* d_in, const int* in_sizes, int n_in,
                              void* d_out, int out_size, void* d_ws, size_t ws_size,
                              hipStream_t stream) {
  const float* src = (const float*)d_in[0];
  const float* gui = (const float*)d_in[1];
  const float* Wq  = (const float*)d_in[2];
  const float* Wk  = (const float*)d_in[3];
  const float* Wv  = (const float*)d_in[4];
  const float* bv  = (const float*)d_in[5];
  const float* gm  = (const float*)d_in[6];
  float* out = (float*)d_out;

  u16* Qb = (u16*)d_ws;                         // 4 MB
  u16* Kb = Qb + (size_t)B_ * N_ * CR_;         // 4 MB
  u16* VF = Kb + (size_t)B_ * N_ * CR_;         // 16 MB (ws total 24 MB)

  u16* inT = (u16*)d_out;                       // 16 MB scratch inside d_out
  u16* Wb  = inT + (size_t)B_ * N_ * C_;        // 288 KB

  wprep_kernel<<<dim3(144), dim3(256), 0, stream>>>(Wq, Wk, Wv, Wb);
  transpose_kernel<<<dim3(64, 4, B_), dim3(256), 0, stream>>>(gui, inT);
  projqk_kernel<<<dim3(32, B_), dim3(128), 0, stream>>>(inT, Wb + 64 * 256, Kb);
  projv_kernel<<<dim3(32, B_, 2), dim3(128), 0, stream>>>(inT, Wb + 128 * 256, bv, VF);
  transpose_kernel<<<dim3(64, 4, B_), dim3(256), 0, stream>>>(src, inT);
  projqk_kernel<<<dim3(32, B_), dim3(128), 0, stream>>>(inT, Wb, Qb);

  attn_kernel<<<dim3(1024), dim3(256), 0, stream>>>(Qb, Kb, VF, src, gm, out);
}

// Round 8
// 213.331 us; speedup vs baseline: 1.1818x; 1.1818x over previous
//
#include <hip/hip_runtime.h>
#include <hip/hip_bf16.h>
#include <stdint.h>

// CrossAttention: B=8, C=256, H=W=64 (N=4096), CR=64.
// proj chain (MFMA): wprep -> transpose(gui) -> projK, projV -> transpose(src) -> projQ
//   Qb/Kb frag-linear: [tile(64px)][frag f<8][lane*8] bf16; Vb [b][ch][n] bf16.
// attn: grid 1024 1-D (XCD swizzle: batch = bid&7), 4 waves, 4 blocks/CU.
//   Wave-local 16q x 128ch; swapped QK^T / swapped PV; no-max softmax
//   (offset cancels; overflow guard); K reg prefetch placed AFTER its consumer
//   MFMAs (issue ~1 iter early, compiler-managed waits); V dbuf via gll16.

#define B_ 8
#define C_ 256
#define N_ 4096
#define CR_ 64

typedef unsigned short u16;
typedef __attribute__((ext_vector_type(8))) __bf16 bf16x8;
typedef __attribute__((ext_vector_type(4))) float f32x4;

__device__ __forceinline__ u16 f2bf(float f) {
  union { float f; unsigned int u; } v; v.f = f;
  unsigned int r = (v.u + 0x7fffu + ((v.u >> 16) & 1u)) >> 16;
  return (u16)r;
}
__device__ __forceinline__ unsigned int cvtpk(float a, float b) {
  unsigned int r;
  asm("v_cvt_pk_bf16_f32 %0, %1, %2" : "=v"(r) : "v"(a), "v"(b));
  return r;
}

typedef __attribute__((address_space(1))) const unsigned int gu32_t;
typedef __attribute__((address_space(3))) unsigned int lu32_t;
__device__ __forceinline__ void gll16(const void* g, void* l) {
  __builtin_amdgcn_global_load_lds((gu32_t*)g, (lu32_t*)l, 16, 0, 0);
}

// ---------------- Weight prep ----------------
__global__ __launch_bounds__(256) void wprep_kernel(
    const float* __restrict__ Wq, const float* __restrict__ Wk,
    const float* __restrict__ Wv, u16* __restrict__ Wb)
{
  const int i = (blockIdx.x * 256 + threadIdx.x) * 4;
  const int row = i >> 8;
  float4 v;
  float s = 1.0f;
  if (row < 64)       { v = *(const float4*)(Wq + i); s = 1.44269504f; }
  else if (row < 128) { v = *(const float4*)(Wk + i - 64 * 256); }
  else                { v = *(const float4*)(Wv + i - 128 * 256); }
  u16* o = Wb + i;
  o[0] = f2bf(v.x * s); o[1] = f2bf(v.y * s);
  o[2] = f2bf(v.z * s); o[3] = f2bf(v.w * s);
}

// ---------------- Transpose [C][N] f32 -> [N][C] bf16 ----------------------
__global__ __launch_bounds__(256) void transpose_kernel(
    const float* __restrict__ in, u16* __restrict__ outT)
{
  __shared__ u16 Tl[64 * 66];
  const int t = threadIdx.x;
  const int px0 = blockIdx.x * 64, ch0 = blockIdx.y * 64, b = blockIdx.z;
  const float* ip = in + ((size_t)(b * C_ + ch0)) * N_ + px0;
  const int cx = t >> 4, p4 = (t & 15) * 4;
#pragma unroll
  for (int p = 0; p < 4; ++p) {
    const int ch = cx + p * 16;
    float4 v = *(const float4*)(ip + (size_t)ch * N_ + p4);
    Tl[(p4 + 0) * 66 + ch] = f2bf(v.x);
    Tl[(p4 + 1) * 66 + ch] = f2bf(v.y);
    Tl[(p4 + 2) * 66 + ch] = f2bf(v.z);
    Tl[(p4 + 3) * 66 + ch] = f2bf(v.w);
  }
  __syncthreads();
  const int row = t >> 3, seg = t & 7;
  u16* op = outT + ((size_t)(b * N_) + px0) * C_ + ch0 + seg * 8;
#pragma unroll
  for (int p = 0; p < 2; ++p) {
    const int r2 = row + p * 32;
    *(uint4*)(op + (size_t)r2 * C_) = *(const uint4*)(&Tl[r2 * 66 + seg * 8]);
  }
}

// ---------------- Q/K projection (MFMA), frag-linear output ----------------
__global__ __launch_bounds__(128) void projqk_kernel(
    const u16* __restrict__ inT, const u16* __restrict__ W64, u16* __restrict__ dst)
{
  __shared__ u16 Tl[2 * 64 * 72];
  const int t = threadIdx.x, lane = t & 63, wave = t >> 6;
  const int lg = lane >> 4, lm = lane & 15;
  const int b = blockIdx.y;
  const int px0 = blockIdx.x * 128 + wave * 64;
  const u16* ib = inT + ((size_t)(b * N_) + px0) * C_;

  f32x4 acc[4][4];
  const f32x4 z4 = {0.f, 0.f, 0.f, 0.f};
#pragma unroll
  for (int i = 0; i < 4; ++i)
#pragma unroll
    for (int j = 0; j < 4; ++j) acc[i][j] = z4;

  for (int ks = 0; ks < 8; ++ks) {
    bf16x8 wf[4], pf[4];
#pragma unroll
    for (int mi = 0; mi < 4; ++mi)
      wf[mi] = *(const bf16x8*)(W64 + (mi * 16 + lm) * C_ + ks * 32 + lg * 8);
#pragma unroll
    for (int ni = 0; ni < 4; ++ni)
      pf[ni] = *(const bf16x8*)(ib + (size_t)(ni * 16 + lm) * C_ + ks * 32 + lg * 8);
#pragma unroll
    for (int mi = 0; mi < 4; ++mi)
#pragma unroll
      for (int ni = 0; ni < 4; ++ni)
        acc[mi][ni] = __builtin_amdgcn_mfma_f32_16x16x32_bf16(wf[mi], pf[ni], acc[mi][ni], 0, 0, 0);
  }

  u16* tw = Tl + wave * 64 * 72;
#pragma unroll
  for (int mi = 0; mi < 4; ++mi)
#pragma unroll
    for (int ni = 0; ni < 4; ++ni)
#pragma unroll
      for (int rp = 0; rp < 2; ++rp)
        *(unsigned int*)&tw[(ni * 16 + lm) * 72 + mi * 16 + lg * 4 + rp * 2] =
            cvtpk(acc[mi][ni][rp * 2], acc[mi][ni][rp * 2 + 1]);

  const int tt = b * 64 + blockIdx.x * 2 + wave;
  u16* op = dst + (size_t)tt * 4096 + lane * 8;
#pragma unroll
  for (int f = 0; f < 8; ++f)
    *(uint4*)(op + f * 512) =
        *(const uint4*)(&Tl[(wave * 64 + (f >> 1) * 16 + lm) * 72 + (f & 1) * 32 + lg * 8]);
}

// ---------------- V projection (MFMA) -> Vb [ch][n] ------------------------
__global__ __launch_bounds__(128) void projv_kernel(
    const u16* __restrict__ inT, const u16* __restrict__ Wv256,
    const float* __restrict__ bv, u16* __restrict__ Vb)
{
  const int t = threadIdx.x, lane = t & 63, wave = t >> 6;
  const int lg = lane >> 4, lm = lane & 15;
  const int b = blockIdx.y;
  const int px0 = blockIdx.x * 128;
  const int chb = blockIdx.z * 128 + wave * 64;
  const u16* ib = inT + ((size_t)(b * N_) + px0) * C_;
  const u16* wb = Wv256 + (size_t)chb * C_;

  f32x4 bq[4];
#pragma unroll
  for (int mi = 0; mi < 4; ++mi)
    bq[mi] = *(const f32x4*)(bv + chb + mi * 16 + lg * 4);

  const f32x4 z4 = {0.f, 0.f, 0.f, 0.f};
  for (int pg = 0; pg < 2; ++pg) {
    f32x4 acc[4][4];
#pragma unroll
    for (int i = 0; i < 4; ++i)
#pragma unroll
      for (int j = 0; j < 4; ++j) acc[i][j] = z4;
    for (int ks = 0; ks < 8; ++ks) {
      bf16x8 wf[4], pf[4];
#pragma unroll
      for (int mi = 0; mi < 4; ++mi)
        wf[mi] = *(const bf16x8*)(wb + (mi * 16 + lm) * C_ + ks * 32 + lg * 8);
#pragma unroll
      for (int ni = 0; ni < 4; ++ni)
        pf[ni] = *(const bf16x8*)(ib + (size_t)(pg * 64 + ni * 16 + lm) * C_ + ks * 32 + lg * 8);
#pragma unroll
      for (int mi = 0; mi < 4; ++mi)
#pragma unroll
        for (int ni = 0; ni < 4; ++ni)
          acc[mi][ni] = __builtin_amdgcn_mfma_f32_16x16x32_bf16(wf[mi], pf[ni], acc[mi][ni], 0, 0, 0);
    }
#pragma unroll
    for (int mi = 0; mi < 4; ++mi)
#pragma unroll
      for (int ni = 0; ni < 4; ++ni)
#pragma unroll
        for (int r = 0; r < 4; ++r)
          Vb[((size_t)(b * C_) + chb + mi * 16 + lg * 4 + r) * N_ +
             px0 + pg * 64 + ni * 16 + lm] = f2bf(acc[mi][ni][r] + bq[mi][r]);
  }
}

// ---------------- Flash attention ----------------
// LDS: Vbuf0 [0,16384), Vbuf1 [16384,32768), P [32768,40960).
#define VB1 16384
#define PB  32768

__global__ __launch_bounds__(256, 4) void attn_kernel(
    const u16* __restrict__ Qb, const u16* __restrict__ Kb, const u16* __restrict__ Vb,
    const float* __restrict__ source, const float* __restrict__ gamma,
    float* __restrict__ out)
{
  __shared__ uint4 smem4[2560];  // 40960 B
  char* smem = (char*)smem4;

  const int bid = blockIdx.x;
  const int b = bid & 7;              // XCD-local batch
  const int idx = bid >> 3;           // 0..127
  const int qt = idx & 63;
  const int half = idx >> 6;

  const int t = threadIdx.x;
  const int lane = t & 63;
  const int wave = t >> 6;
  const int lg = lane >> 4;
  const int lm = lane & 15;
  const int q0 = qt * 64;
  const int sw = lm & 7;

  bf16x8 aq[2];
  {
    const u16* qp = Qb + (((size_t)(b * 64 + qt) * 8 + wave * 2) * 512) + lane * 8;
    aq[0] = *(const bf16x8*)qp;
    aq[1] = *(const bf16x8*)(qp + 512);
  }

  const u16* KbT = Kb + (size_t)b * N_ * CR_;
  const char* VbB = (const char*)(Vb + ((size_t)(b * C_) + half * 128) * N_);

  const int srow = t >> 3, cslot = t & 7;
  unsigned int vgo[4];
#pragma unroll
  for (int i = 0; i < 4; ++i) {
    int row = i * 32 + srow;
    int cl = cslot ^ (row & 7);
    vgo[i] = (unsigned int)((row * N_ + cl * 8) * 2);
  }

  f32x4 accv[8];
  const f32x4 zero4 = {0.f, 0.f, 0.f, 0.f};
#pragma unroll
  for (int i = 0; i < 8; ++i) accv[i] = zero4;
  float mrow = 0.f, lrow = 0.f;   // no-max softmax: offset starts at 0

  bf16x8 kC[8];
  char* pslice = smem + PB + wave * 2048 + lm * 128;

#define STAGEV(KTILE, VOFF) do {                                             \
    unsigned int vadd_ = (unsigned int)((KTILE) * 128);                      \
    _Pragma("unroll")                                                        \
    for (int i = 0; i < 4; ++i)                                              \
      gll16(VbB + vgo[i] + vadd_, smem + (VOFF) + i * 4096 + wave * 1024);   \
  } while (0)

#define LOADK(KT) do {                                                       \
    const u16* kb_ = KbT + (size_t)(KT) * 4096 + lane * 8;                   \
    _Pragma("unroll")                                                        \
    for (int f = 0; f < 8; ++f)                                              \
      kC[f] = *(const bf16x8*)(kb_ + f * 512);                               \
  } while (0)

// Iter T: barrier (drains loads issued at top of T-1: V(T) staged, K(T) in
// regs) -> stage V(T+1) -> S(T) MFMAs consume kC -> refill kC = K(T+1)
// (placed AFTER its consumers; ~1 iter of latency cover, compiler-managed
// waits) -> no-max softmax -> P via LDS -> PV(T) from VCUR.
#define ITER(KT, VCUR, VNXT) do {                                            \
    __syncthreads();                                                         \
    const int ktn_ = ((KT) + 1 < 64) ? (KT) + 1 : 63;                        \
    STAGEV(ktn_, VNXT);                                                      \
    f32x4 sf[4];                                                             \
    __builtin_amdgcn_s_setprio(1);                                           \
    _Pragma("unroll")                                                        \
    for (int kf = 0; kf < 4; ++kf) {                                         \
      sf[kf] = zero4;                                                        \
      sf[kf] = __builtin_amdgcn_mfma_f32_16x16x32_bf16(kC[kf*2], aq[0], sf[kf], 0, 0, 0); \
      sf[kf] = __builtin_amdgcn_mfma_f32_16x16x32_bf16(kC[kf*2+1], aq[1], sf[kf], 0, 0, 0); \
    }                                                                        \
    __builtin_amdgcn_s_setprio(0);                                           \
    LOADK(ktn_);                                                             \
    float s_ = 0.f;                                                          \
    _Pragma("unroll")                                                        \
    for (int kf = 0; kf < 4; ++kf)                                           \
      _Pragma("unroll")                                                      \
      for (int r = 0; r < 4; ++r) {                                          \
        float e_ = __builtin_amdgcn_exp2f(sf[kf][r] - mrow);                 \
        sf[kf][r] = e_;                                                      \
        s_ += e_;                                                            \
      }                                                                      \
    s_ += __shfl_xor(s_, 16);                                                \
    s_ += __shfl_xor(s_, 32);                                                \
    lrow += s_;                                                              \
    if (lrow > 1e30f) {  /* robustness guard; never triggers for sane data */\
      const float dsc_ = 5.421010862e-20f;  /* 2^-64 */                      \
      lrow *= dsc_;                                                          \
      mrow += 64.f;                                                          \
      _Pragma("unroll")                                                      \
      for (int cf = 0; cf < 8; ++cf)                                         \
        _Pragma("unroll")                                                    \
        for (int r = 0; r < 4; ++r) accv[cf][r] *= dsc_;                     \
    }                                                                        \
    _Pragma("unroll")                                                        \
    for (int kf = 0; kf < 4; ++kf) {                                         \
      uint2 w2_;                                                             \
      w2_.x = cvtpk(sf[kf][0], sf[kf][1]);                                   \
      w2_.y = cvtpk(sf[kf][2], sf[kf][3]);                                   \
      *reinterpret_cast<uint2*>(                                             \
          pslice + (((kf * 2 + (lg >> 1)) ^ sw) << 4) + ((lg & 1) << 3)) = w2_; \
    }                                                                        \
    bf16x8 pb0_ = *reinterpret_cast<const bf16x8*>(pslice + ((lg ^ sw) << 4)); \
    bf16x8 pb1_ = *reinterpret_cast<const bf16x8*>(pslice + (((4 + lg) ^ sw) << 4)); \
    __builtin_amdgcn_s_setprio(1);                                           \
    _Pragma("unroll")                                                        \
    for (int cf = 0; cf < 8; ++cf) {                                         \
      bf16x8 vf_ = *reinterpret_cast<const bf16x8*>(                         \
          smem + (VCUR) + (cf * 16 + lm) * 128 + ((lg ^ sw) << 4));          \
      accv[cf] = __builtin_amdgcn_mfma_f32_16x16x32_bf16(vf_, pb0_, accv[cf], 0, 0, 0); \
    }                                                                        \
    _Pragma("unroll")                                                        \
    for (int cf = 0; cf < 8; ++cf) {                                         \
      bf16x8 vf_ = *reinterpret_cast<const bf16x8*>(                         \
          smem + (VCUR) + (cf * 16 + lm) * 128 + (((4 + lg) ^ sw) << 4));    \
      accv[cf] = __builtin_amdgcn_mfma_f32_16x16x32_bf16(vf_, pb1_, accv[cf], 0, 0, 0); \
    }                                                                        \
    __builtin_amdgcn_s_setprio(0);                                           \
  } while (0)

  // prologue: V(0) staging + K(0) in flight; first barrier drains them
  STAGEV(0, 0);
  LOADK(0);
  for (int kt2 = 0; kt2 < 64; kt2 += 2) {
    ITER(kt2,     0,   VB1);
    ITER(kt2 + 1, VB1, 0);
  }
  asm volatile("s_waitcnt vmcnt(0)" ::: "memory");  // drain trailing LDS-DMA

  // ---- epilogue: out[b][ch][q0+wave*16+lm] = accv*inv + source ----
  const float inv = gamma[0] / fmaxf(lrow, 1e-37f);
#pragma unroll
  for (int cf = 0; cf < 8; ++cf)
#pragma unroll
    for (int r = 0; r < 4; ++r) {
      const int ch = half * 128 + cf * 16 + lg * 4 + r;
      size_t gi = ((size_t)(b * C_ + ch)) * N_ + q0 + wave * 16 + lm;
      out[gi] = accv[cf][r] * inv + source[gi];
    }
}

extern "C" void kernel_launch(void* const* d_in, const int* in_sizes, int n_in,
                              void* d_out, int out_size, void* d_ws, size_t ws_size,
                              hipStream_t stream) {
  const float* src = (const float*)d_in[0];
  const float* gui = (const float*)d_in[1];
  const float* Wq  = (const float*)d_in[2];
  const float* Wk  = (const float*)d_in[3];
  const float* Wv  = (const float*)d_in[4];
  const float* bv  = (const float*)d_in[5];
  const float* gm  = (const float*)d_in[6];
  float* out = (float*)d_out;

  u16* Qb = (u16*)d_ws;                         // 4 MB
  u16* Kb = Qb + (size_t)B_ * N_ * CR_;         // 4 MB
  u16* Vb = Kb + (size_t)B_ * N_ * CR_;         // 16 MB (ws total 24 MB)

  u16* inT = (u16*)d_out;                       // 16 MB scratch inside d_out
  u16* Wb  = inT + (size_t)B_ * N_ * C_;        // 288 KB

  wprep_kernel<<<dim3(144), dim3(256), 0, stream>>>(Wq, Wk, Wv, Wb);
  transpose_kernel<<<dim3(64, 4, B_), dim3(256), 0, stream>>>(gui, inT);
  projqk_kernel<<<dim3(32, B_), dim3(128), 0, stream>>>(inT, Wb + 64 * 256, Kb);
  projv_kernel<<<dim3(32, B_, 2), dim3(128), 0, stream>>>(inT, Wb + 128 * 256, bv, Vb);
  transpose_kernel<<<dim3(64, 4, B_), dim3(256), 0, stream>>>(src, inT);
  projqk_kernel<<<dim3(32, B_), dim3(128), 0, stream>>>(inT, Wb, Qb);

  attn_kernel<<<dim3(1024), dim3(256), 0, stream>>>(Qb, Kb, Vb, src, gm, out);
}